// Round 5
// baseline (502.603 us; speedup 1.0000x reference)
//
#include <hip/hip_runtime.h>
#include <math.h>

#define MEM 32768
#define UNITS 128
#define BATCH 256
#define IN_DIM 512
#define ZDIM 512      // 4*UNITS
#define CI_DIM 768    // IN_DIM + UNITS(r) + UNITS(h)

// ---- d_out offsets (floats), reference return order ----
#define OFF_READ   0
#define OFF_MEMORY (OFF_READ + BATCH*UNITS)        // 32768
#define OFF_CWU    (OFF_MEMORY + MEM*UNITS)        // 4227072
#define OFF_CWLU   (OFF_CWU + MEM*BATCH)           // 12615680
#define OFF_CWR    (OFF_CWLU + MEM*BATCH)          // 21004288
#define OFF_CWW    (OFF_CWR + MEM*BATCH)           // 29392896
#define OFF_H      (OFF_CWW + MEM*BATCH)           // 37781504
#define OFF_C      (OFF_H + BATCH*UNITS)           // 37814272

// ---- ws offsets (bytes) ----
#define WS_HT     0                                // float[UNITS*BATCH] (scaled h^T)
#define WS_COLMIN (UNITS*BATCH*4)                  // u64[BATCH]          (131072)
#define WS_B2H    (WS_COLMIN + BATCH*8)            // short8 raw-h frags  (133120)
#define WS_B2L    (WS_B2H + 65536)
#define WS_BHI    (WS_B2L + 65536)                 // short8 swizzled hT hi (64 KB)
#define WS_BLO    (WS_BHI + 65536)                 // ends 395264
#define WS_PART   (512*1024)                       // float[64][BATCH][UNITS] split-K partials
#define PART_BYTES (64*BATCH*UNITS*4)              // 8 MB

typedef __attribute__((ext_vector_type(8))) short short8;
typedef __attribute__((ext_vector_type(4))) float f32x4;

__device__ __forceinline__ float sigf(float x) { return 1.0f / (1.0f + __expf(-x)); }
// bf16 round-to-nearest-even from f32 (bits as short)
__device__ __forceinline__ short bf16r(float x) {
    unsigned u = __float_as_uint(x);
    return (short)((u + 0x7fffu + ((u >> 16) & 1u)) >> 16);
}
__device__ __forceinline__ float bf16f(short h) {
    return __uint_as_float(((unsigned)(unsigned short)h) << 16);
}

// ------------------------------------------------------------------
// K1: LSTM cell (4 rows/block), h/c outputs, h-norm, scaled h^T to ws
// ------------------------------------------------------------------
__global__ __launch_bounds__(512) void k_lstm(
    const float* __restrict__ inp, const float* __restrict__ r_tm1,
    const float* __restrict__ h_tm1, const float* __restrict__ c_tm1,
    const float* __restrict__ W, const float* __restrict__ RW,
    const float* __restrict__ bias,
    float* __restrict__ out, float* __restrict__ hT)
{
    __shared__ float ci[4][CI_DIM];
    __shared__ float zl[4][ZDIM];
    __shared__ float part[8];
    const int t = threadIdx.x;
    const int row0 = blockIdx.x * 4;

    for (int i = t; i < 4 * CI_DIM; i += 512) {
        int r = i / CI_DIM, j = i - r * CI_DIM;
        int row = row0 + r;
        float v;
        if (j < IN_DIM)              v = inp[row * IN_DIM + j];
        else if (j < IN_DIM + UNITS) v = r_tm1[row * UNITS + (j - IN_DIM)];
        else                         v = h_tm1[row * UNITS + (j - IN_DIM - UNITS)];
        ci[r][j] = v;
    }
    __syncthreads();

    float b = bias[t];
    float z0 = b, z1 = b, z2 = b, z3 = b;
    for (int k4 = 0; k4 < (IN_DIM + UNITS) / 4; ++k4) {
        float w0 = W[(k4 * 4 + 0) * ZDIM + t];
        float w1 = W[(k4 * 4 + 1) * ZDIM + t];
        float w2 = W[(k4 * 4 + 2) * ZDIM + t];
        float w3 = W[(k4 * 4 + 3) * ZDIM + t];
        float4 a0 = *(const float4*)&ci[0][k4 * 4];
        float4 a1 = *(const float4*)&ci[1][k4 * 4];
        float4 a2 = *(const float4*)&ci[2][k4 * 4];
        float4 a3 = *(const float4*)&ci[3][k4 * 4];
        z0 += a0.x * w0 + a0.y * w1 + a0.z * w2 + a0.w * w3;
        z1 += a1.x * w0 + a1.y * w1 + a1.z * w2 + a1.w * w3;
        z2 += a2.x * w0 + a2.y * w1 + a2.z * w2 + a2.w * w3;
        z3 += a3.x * w0 + a3.y * w1 + a3.z * w2 + a3.w * w3;
    }
    for (int k4 = 0; k4 < UNITS / 4; ++k4) {
        float w0 = RW[(k4 * 4 + 0) * ZDIM + t];
        float w1 = RW[(k4 * 4 + 1) * ZDIM + t];
        float w2 = RW[(k4 * 4 + 2) * ZDIM + t];
        float w3 = RW[(k4 * 4 + 3) * ZDIM + t];
        const int base = IN_DIM + UNITS + k4 * 4;
        float4 a0 = *(const float4*)&ci[0][base];
        float4 a1 = *(const float4*)&ci[1][base];
        float4 a2 = *(const float4*)&ci[2][base];
        float4 a3 = *(const float4*)&ci[3][base];
        z0 += a0.x * w0 + a0.y * w1 + a0.z * w2 + a0.w * w3;
        z1 += a1.x * w0 + a1.y * w1 + a1.z * w2 + a1.w * w3;
        z2 += a2.x * w0 + a2.y * w1 + a2.z * w2 + a2.w * w3;
        z3 += a3.x * w0 + a3.y * w1 + a3.z * w2 + a3.w * w3;
    }
    zl[0][t] = z0; zl[1][t] = z1; zl[2][t] = z2; zl[3][t] = z3;
    __syncthreads();

    const int r = t >> 7, u = t & 127;
    const int row = row0 + r;
    float iv = zl[r][u], fv = zl[r][UNITS + u], gv = zl[r][2 * UNITS + u], ov = zl[r][3 * UNITS + u];
    float ig = sigf(iv), fg = sigf(fv), og = sigf(ov);
    float gt = tanhf(gv);
    float cn = fg * c_tm1[row * UNITS + u] + ig * gt;
    float hn = og * tanhf(cn);
    out[OFF_C + row * UNITS + u] = cn;
    out[OFF_H + row * UNITS + u] = hn;

    float s = hn * hn;
    for (int d = 1; d < 64; d <<= 1) s += __shfl_xor(s, d, 64);
    int wave = t >> 6;
    if ((t & 63) == 0) part[wave] = s;
    __syncthreads();
    float inv = rsqrtf(fmaxf(part[2 * r] + part[2 * r + 1], 1e-12f));
    hT[u * BATCH + row] = hn * inv;
}

// ------------------------------------------------------------------
// K2: swizzle normalized h^T into MFMA layout (bf16 hi/lo), and
// (blocks 0..7) swizzle raw h into K-major MFMA-B fragments for k_memory.
// ------------------------------------------------------------------
__global__ __launch_bounds__(256) void k_hswz(
    const float* __restrict__ hT, short8* __restrict__ Bhi, short8* __restrict__ Blo,
    const float* __restrict__ h, short8* __restrict__ B2h, short8* __restrict__ B2l)
{
    const int t = threadIdx.x, bt = blockIdx.x;
    const int s = t >> 6, L = t & 63;
    const int b = bt * 16 + (L & 15);
    const int k0 = s * 32 + (L >> 4) * 8;
    short8 hi, lo;
#pragma unroll
    for (int j = 0; j < 8; ++j) {
        float x = hT[(k0 + j) * BATCH + b];
        short hb = bf16r(x);
        hi[j] = hb;
        lo[j] = bf16r(x - bf16f(hb));
    }
    Bhi[bt * 256 + t] = hi;
    Blo[bt * 256 + t] = lo;

    if (bt < 8) {  // raw-h fragments (K = batch), block bt covers b-rows bt*32..+31
        const int u = t & 127, op = t >> 7;
#pragma unroll
        for (int oo = 0; oo < 2; ++oo) {
            const int oct = op + 2 * oo;
            short8 h2, l2;
#pragma unroll
            for (int j = 0; j < 8; ++j) {
                float x = h[(bt * 32 + oct * 8 + j) * UNITS + u];
                short hb = bf16r(x);
                h2[j] = hb;
                l2[j] = bf16r(x - bf16f(hb));
            }
            B2h[(bt * 8 + (u >> 4)) * 64 + (u & 15) + 16 * oct] = h2;
            B2l[(bt * 8 + (u >> 4)) * 64 + (u & 15) + 16 * oct] = l2;
        }
    }
}

// ------------------------------------------------------------------
// K3 v6: swapped-operand cos+softmax. Wave = 16 memrows, NO LDS, NO
// barriers. mfma(A=key frags [ws], B=mem frags) -> C^T: lane holds 64 of
// 256 batch entries of its memrow (col=lane&15=memrow, row=batch).
// Softmax over batch = in-reg reduce + 2 shuffles (xor16/xor32).
// Norm of m rows = in-reg + 2 shuffles. colmin moved to k_colmin.
// ------------------------------------------------------------------
__global__ __launch_bounds__(256, 4) void k_cos_softmax(
    const float* __restrict__ m,
    const short8* __restrict__ Bhi, const short8* __restrict__ Blo,
    const float* __restrict__ cwr_tm1, const float* __restrict__ cwlu_tm1,
    const float* __restrict__ cwu_tm1, const float* __restrict__ wgp,
    float* __restrict__ out)
{
    const int t = threadIdx.x;
    const int w = t >> 6, L = t & 63;
    const int row = blockIdx.x * 64 + w * 16 + (L & 15);   // wave's memrow
    const int q = L >> 4;

    // ---- load this lane's 32 k's of its m row (4 K-steps x 8) ----
    float x[4][8];
#pragma unroll
    for (int s = 0; s < 4; ++s) {
        const float* src = &m[(size_t)row * UNITS + s * 32 + q * 8];
        float4 v0 = *(const float4*)src;
        float4 v1 = *(const float4*)(src + 4);
        x[s][0] = v0.x; x[s][1] = v0.y; x[s][2] = v0.z; x[s][3] = v0.w;
        x[s][4] = v1.x; x[s][5] = v1.y; x[s][6] = v1.z; x[s][7] = v1.w;
    }
    // ---- row L2-norm: in-reg + 2 shuffles across q groups ----
    float ss = 0.f;
#pragma unroll
    for (int s = 0; s < 4; ++s)
#pragma unroll
        for (int j = 0; j < 8; ++j) ss += x[s][j] * x[s][j];
    ss += __shfl_xor(ss, 16, 64);
    ss += __shfl_xor(ss, 32, 64);
    const float inv = rsqrtf(fmaxf(ss, 1e-12f));

    // ---- build mem B-frags (bf16 hi/lo) in registers ----
    short8 mh[4], ml[4];
#pragma unroll
    for (int s = 0; s < 4; ++s) {
#pragma unroll
        for (int j = 0; j < 8; ++j) {
            float xv = x[s][j] * inv;
            short hb = bf16r(xv);
            mh[s][j] = hb;
            ml[s][j] = bf16r(xv - bf16f(hb));
        }
    }

    // ---- MFMA: acc[bt] = S^T tile (batch bt*16.. x this wave's memrows) ----
    f32x4 acc[16];
#pragma unroll
    for (int bt = 0; bt < 16; ++bt) { acc[bt][0] = 0.f; acc[bt][1] = 0.f; acc[bt][2] = 0.f; acc[bt][3] = 0.f; }
#pragma unroll
    for (int bt = 0; bt < 16; ++bt) {
#pragma unroll
        for (int s = 0; s < 4; ++s) {
            short8 kh = Bhi[(bt * 4 + s) * 64 + L];
            short8 kl = Blo[(bt * 4 + s) * 64 + L];
            acc[bt] = __builtin_amdgcn_mfma_f32_16x16x32_bf16(kh, mh[s], acc[bt], 0, 0, 0);
            acc[bt] = __builtin_amdgcn_mfma_f32_16x16x32_bf16(kh, ml[s], acc[bt], 0, 0, 0);
            acc[bt] = __builtin_amdgcn_mfma_f32_16x16x32_bf16(kl, mh[s], acc[bt], 0, 0, 0);
        }
    }

    // ---- softmax over batch (256) for this memrow ----
    float mx = acc[0][0];
#pragma unroll
    for (int bt = 0; bt < 16; ++bt)
#pragma unroll
        for (int r = 0; r < 4; ++r) mx = fmaxf(mx, acc[bt][r]);
    mx = fmaxf(mx, __shfl_xor(mx, 16, 64));
    mx = fmaxf(mx, __shfl_xor(mx, 32, 64));
    float sum = 0.f;
#pragma unroll
    for (int bt = 0; bt < 16; ++bt)
#pragma unroll
        for (int r = 0; r < 4; ++r) {
            float e = __expf(acc[bt][r] - mx);
            acc[bt][r] = e;
            sum += e;
        }
    sum += __shfl_xor(sum, 16, 64);
    sum += __shfl_xor(sum, 32, 64);
    const float is = 1.0f / sum;

    // ---- outputs: c_wr / c_ww / c_wu, float4 per bt-tile ----
    const float wg = sigf(wgp[0]);
    const float wgc = 1.0f - wg;
    const size_t base = (size_t)row * BATCH;
#pragma unroll
    for (int bt = 0; bt < 16; ++bt) {
        const int c = bt * 16 + q * 4;
        float4 wr;
        wr.x = acc[bt][0] * is; wr.y = acc[bt][1] * is;
        wr.z = acc[bt][2] * is; wr.w = acc[bt][3] * is;
        *(float4*)&out[OFF_CWR + base + c] = wr;

        float4 pr = *(const float4*)&cwr_tm1[base + c];
        float4 pl = *(const float4*)&cwlu_tm1[base + c];
        float4 ww;
        ww.x = wg * pr.x + wgc + pl.x; ww.y = wg * pr.y + wgc + pl.y;
        ww.z = wg * pr.z + wgc + pl.z; ww.w = wg * pr.w + wgc + pl.w;
        *(float4*)&out[OFF_CWW + base + c] = ww;

        float4 pu = *(const float4*)&cwu_tm1[base + c];
        float4 wu;
        wu.x = 0.95f * pu.x + wr.x + ww.x; wu.y = 0.95f * pu.y + wr.y + ww.y;
        wu.z = 0.95f * pu.z + wr.z + ww.z; wu.w = 0.95f * pu.w + wr.w + ww.w;
        *(float4*)&out[OFF_CWU + base + c] = wu;
    }
}

// ------------------------------------------------------------------
// K4 v2: per-batch-column min of c_wu (packed key: bits<<32 | MEM-1-row,
// min-key => min value, largest index on ties). 256 blocks x 128 rows.
// ------------------------------------------------------------------
__global__ __launch_bounds__(256) void k_colmin(
    const float* __restrict__ cwu, unsigned long long* __restrict__ colmin)
{
    const int t = threadIdx.x;            // batch column
    const int r0 = blockIdx.x * 128;
    unsigned long long mk = ~0ULL;
    const float* p = &cwu[(size_t)r0 * BATCH + t];
#pragma unroll 4
    for (int i = 0; i < 128; ++i) {
        float v = p[(size_t)i * BATCH];
        unsigned long long k = ((unsigned long long)__float_as_uint(v) << 32)
                             | (unsigned)(MEM - 1 - (r0 + i));
        if (k < mk) mk = k;
    }
    if (mk < colmin[t]) atomicMin(&colmin[t], mk);
}

// ------------------------------------------------------------------
// K5 v2: c_wlu = (c_wu <= minv[b]); minv decoded from colmin in LDS.
// 4 consecutive float4s per thread.
// ------------------------------------------------------------------
__global__ __launch_bounds__(256) void k_wlu(const float* __restrict__ cwu,
                                             const unsigned long long* __restrict__ colmin,
                                             float* __restrict__ wlu)
{
    __shared__ float mvs[256];
    const int t = threadIdx.x;
    mvs[t] = __uint_as_float((unsigned)(colmin[t] >> 32));
    __syncthreads();
    const int i0 = (blockIdx.x * 256 + t) * 4;   // float4 index
#pragma unroll
    for (int j = 0; j < 4; ++j) {
        const int i = i0 + j;
        float4 v = *(const float4*)&cwu[(size_t)i * 4];
        float4 mv = *(const float4*)&mvs[(i & 63) * 4];
        float4 r;
        r.x = (v.x <= mv.x) ? 1.0f : 0.0f;
        r.y = (v.y <= mv.y) ? 1.0f : 0.0f;
        r.z = (v.z <= mv.z) ? 1.0f : 0.0f;
        r.w = (v.w <= mv.w) ? 1.0f : 0.0f;
        *(float4*)&wlu[(size_t)i * 4] = r;
    }
}

// ------------------------------------------------------------------
// K7 v3: read = c_wr^T @ m via MFMA bf16 hi/lo split, split-K.
// ------------------------------------------------------------------
__global__ __launch_bounds__(256) void k_read(
    const float* __restrict__ cwr, const float* __restrict__ m,
    float* __restrict__ dst, int use_part)
{
    __shared__ short8 Ah[4 * 64], Al[4 * 64];
    __shared__ short8 Bh[8 * 64], Bl[8 * 64];
    const int t = threadIdx.x;
    const int w = t >> 6, L = t & 63;
    const int kc = blockIdx.x >> 2;
    const int bq = blockIdx.x & 3;
    const int k0 = kc * 512;

    const int ab = t & 63;           // b within quarter (A staging role)
    const int aoct = t >> 6;         // 0..3
    const int bu = t & 127;          // u (B staging role)
    const int bop = t >> 7;          // 0..1

    f32x4 zero = {0.f, 0.f, 0.f, 0.f};
    f32x4 acc[8];
#pragma unroll
    for (int i = 0; i < 8; ++i) acc[i] = zero;

    float axr[8];
    float bxr[2][8];
#pragma unroll
    for (int j = 0; j < 8; ++j)
        axr[j] = cwr[(size_t)(k0 + aoct * 8 + j) * BATCH + bq * 64 + ab];
#pragma unroll
    for (int oo = 0; oo < 2; ++oo)
#pragma unroll
        for (int j = 0; j < 8; ++j)
            bxr[oo][j] = m[(size_t)(k0 + (bop + 2 * oo) * 8 + j) * UNITS + bu];

    for (int ks = 0; ks < 16; ++ks) {
        {   // convert & store fragments
            short8 hi, lo;
#pragma unroll
            for (int j = 0; j < 8; ++j) {
                short hb = bf16r(axr[j]);
                hi[j] = hb;
                lo[j] = bf16r(axr[j] - bf16f(hb));
            }
            Ah[(ab >> 4) * 64 + (ab & 15) + 16 * aoct] = hi;
            Al[(ab >> 4) * 64 + (ab & 15) + 16 * aoct] = lo;
#pragma unroll
            for (int oo = 0; oo < 2; ++oo) {
                short8 h2, l2;
#pragma unroll
                for (int j = 0; j < 8; ++j) {
                    short hb = bf16r(bxr[oo][j]);
                    h2[j] = hb;
                    l2[j] = bf16r(bxr[oo][j] - bf16f(hb));
                }
                Bh[(bu >> 4) * 64 + (bu & 15) + 16 * (bop + 2 * oo)] = h2;
                Bl[(bu >> 4) * 64 + (bu & 15) + 16 * (bop + 2 * oo)] = l2;
            }
        }
        __syncthreads();
        if (ks < 15) {  // prefetch next tiles under the MFMA phase
            const int kb = k0 + (ks + 1) * 32;
#pragma unroll
            for (int j = 0; j < 8; ++j)
                axr[j] = cwr[(size_t)(kb + aoct * 8 + j) * BATCH + bq * 64 + ab];
#pragma unroll
            for (int oo = 0; oo < 2; ++oo)
#pragma unroll
                for (int j = 0; j < 8; ++j)
                    bxr[oo][j] = m[(size_t)(kb + (bop + 2 * oo) * 8 + j) * UNITS + bu];
        }
        short8 a_h = Ah[w * 64 + L], a_l = Al[w * 64 + L];
#pragma unroll
        for (int nt = 0; nt < 8; ++nt) {
            short8 b_h = Bh[nt * 64 + L], b_l = Bl[nt * 64 + L];
            acc[nt] = __builtin_amdgcn_mfma_f32_16x16x32_bf16(a_h, b_h, acc[nt], 0, 0, 0);
            acc[nt] = __builtin_amdgcn_mfma_f32_16x16x32_bf16(a_h, b_l, acc[nt], 0, 0, 0);
            acc[nt] = __builtin_amdgcn_mfma_f32_16x16x32_bf16(a_l, b_h, acc[nt], 0, 0, 0);
        }
        __syncthreads();
    }

    const int rb = bq * 64 + w * 16 + (L >> 4) * 4;
    const int u0 = L & 15;
    if (use_part) {
        float* p = dst + (size_t)kc * (BATCH * UNITS);
#pragma unroll
        for (int nt = 0; nt < 8; ++nt)
#pragma unroll
            for (int r = 0; r < 4; ++r)
                p[(rb + r) * UNITS + nt * 16 + u0] = acc[nt][r];
    } else {
#pragma unroll
        for (int nt = 0; nt < 8; ++nt)
#pragma unroll
            for (int r = 0; r < 4; ++r)
                atomicAdd(&dst[(rb + r) * UNITS + nt * 16 + u0], acc[nt][r]);
    }
}

// ------------------------------------------------------------------
// K6 v4: memory = c_ww @ h + (BATCH - count)*m, MFMA bf16 hi/lo split.
// Fused: per-block argmin counts decoded from colmin (LDS), and the
// split-K 'read' reduction (block owns slice [bid*128, +128)).
// ------------------------------------------------------------------
__global__ __launch_bounds__(256) void k_memory(
    const float* __restrict__ cww, const short8* __restrict__ B2h,
    const short8* __restrict__ B2l, const float* __restrict__ m,
    const unsigned long long* __restrict__ colmin,
    const float* __restrict__ part, float* __restrict__ mem_out,
    float* __restrict__ read_out, int use_part)
{
    __shared__ short8 Ah[8 * 64], Al[8 * 64];
    __shared__ int cnt[128];
    const int t = threadIdx.x;
    const int w = t >> 6, L = t & 63;
    const int m0 = blockIdx.x * 128;
    const int mr = t & 127;          // m-row within block (A staging role)
    const int op = t >> 7;           // octet pair selector

    if (t < 128) cnt[t] = 0;
    __syncthreads();
    {   // count argmins falling in this block's row range
        unsigned long long k = colmin[t];
        int idx = MEM - 1 - (int)(unsigned)(k & 0xffffffffu);
        unsigned rel = (unsigned)(idx - m0);
        if (rel < 128u) atomicAdd(&cnt[rel], 1);
    }
    if (use_part && t < 128) {   // fused split-K reduce for 'read'
        const int slice = blockIdx.x * 128;
        float s = 0.f;
#pragma unroll
        for (int c = 0; c < 64; ++c) s += part[c * (BATCH * UNITS) + slice + t];
        read_out[slice + t] = s;
    }

    f32x4 zero = {0.f, 0.f, 0.f, 0.f};
    f32x4 acc[2][8];
#pragma unroll
    for (int mi = 0; mi < 2; ++mi)
#pragma unroll
        for (int nt = 0; nt < 8; ++nt) acc[mi][nt] = zero;

    // prefetch A tile for ks=0: cww[m0+mr][oct*8 .. +8]
    float ax[2][8];
#pragma unroll
    for (int oo = 0; oo < 2; ++oo) {
        const float* src = &cww[(size_t)(m0 + mr) * BATCH + (op + 2 * oo) * 8];
        float4 v0 = *(const float4*)src;
        float4 v1 = *(const float4*)(src + 4);
        ax[oo][0] = v0.x; ax[oo][1] = v0.y; ax[oo][2] = v0.z; ax[oo][3] = v0.w;
        ax[oo][4] = v1.x; ax[oo][5] = v1.y; ax[oo][6] = v1.z; ax[oo][7] = v1.w;
    }

    for (int ks = 0; ks < 8; ++ks) {
        // convert & store A fragments
#pragma unroll
        for (int oo = 0; oo < 2; ++oo) {
            const int oct = op + 2 * oo;
            short8 hi, lo;
#pragma unroll
            for (int j = 0; j < 8; ++j) {
                short hb = bf16r(ax[oo][j]);
                hi[j] = hb;
                lo[j] = bf16r(ax[oo][j] - bf16f(hb));
            }
            Ah[(mr >> 4) * 64 + (mr & 15) + 16 * oct] = hi;
            Al[(mr >> 4) * 64 + (mr & 15) + 16 * oct] = lo;
        }
        __syncthreads();
        if (ks < 7) {   // prefetch next A tile under the MFMA phase
#pragma unroll
            for (int oo = 0; oo < 2; ++oo) {
                const float* src = &cww[(size_t)(m0 + mr) * BATCH + (ks + 1) * 32 + (op + 2 * oo) * 8];
                float4 v0 = *(const float4*)src;
                float4 v1 = *(const float4*)(src + 4);
                ax[oo][0] = v0.x; ax[oo][1] = v0.y; ax[oo][2] = v0.z; ax[oo][3] = v0.w;
                ax[oo][4] = v1.x; ax[oo][5] = v1.y; ax[oo][6] = v1.z; ax[oo][7] = v1.w;
            }
        }
        short8 a_h0 = Ah[(2 * w) * 64 + L],     a_l0 = Al[(2 * w) * 64 + L];
        short8 a_h1 = Ah[(2 * w + 1) * 64 + L], a_l1 = Al[(2 * w + 1) * 64 + L];
#pragma unroll
        for (int nt = 0; nt < 8; ++nt) {
            short8 b_h = B2h[(ks * 8 + nt) * 64 + L];
            short8 b_l = B2l[(ks * 8 + nt) * 64 + L];
            acc[0][nt] = __builtin_amdgcn_mfma_f32_16x16x32_bf16(a_h0, b_h, acc[0][nt], 0, 0, 0);
            acc[0][nt] = __builtin_amdgcn_mfma_f32_16x16x32_bf16(a_h0, b_l, acc[0][nt], 0, 0, 0);
            acc[0][nt] = __builtin_amdgcn_mfma_f32_16x16x32_bf16(a_l0, b_h, acc[0][nt], 0, 0, 0);
            acc[1][nt] = __builtin_amdgcn_mfma_f32_16x16x32_bf16(a_h1, b_h, acc[1][nt], 0, 0, 0);
            acc[1][nt] = __builtin_amdgcn_mfma_f32_16x16x32_bf16(a_h1, b_l, acc[1][nt], 0, 0, 0);
            acc[1][nt] = __builtin_amdgcn_mfma_f32_16x16x32_bf16(a_l1, b_h, acc[1][nt], 0, 0, 0);
        }
        __syncthreads();
    }

    // epilogue: C row = mt*16 + (L>>4)*4 + r, col = nt*16 + (L&15)
#pragma unroll
    for (int mi = 0; mi < 2; ++mi) {
#pragma unroll
        for (int r = 0; r < 4; ++r) {
            const int rl = (2 * w + mi) * 16 + (L >> 4) * 4 + r;
            const int row = m0 + rl;
            const float sc = (float)(BATCH - cnt[rl]);
#pragma unroll
            for (int nt = 0; nt < 8; ++nt) {
                const int u = nt * 16 + (L & 15);
                mem_out[row * UNITS + u] = acc[mi][nt][r] + sc * m[row * UNITS + u];
            }
        }
    }
}

// ------------------------------------------------------------------
extern "C" void kernel_launch(void* const* d_in, const int* in_sizes, int n_in,
                              void* d_out, int out_size, void* d_ws, size_t ws_size,
                              hipStream_t stream)
{
    (void)in_sizes; (void)n_in; (void)out_size;
    const float* inp      = (const float*)d_in[0];
    const float* r_tm1    = (const float*)d_in[1];
    const float* m_tm1    = (const float*)d_in[2];
    const float* cwu_tm1  = (const float*)d_in[3];
    const float* cwlu_tm1 = (const float*)d_in[4];
    const float* cwr_tm1  = (const float*)d_in[5];
    // d_in[6] = c_ww_tm1: unused by the reference
    const float* h_tm1    = (const float*)d_in[7];
    const float* c_tm1    = (const float*)d_in[8];
    const float* W        = (const float*)d_in[9];
    const float* RW       = (const float*)d_in[10];
    const float* bias     = (const float*)d_in[11];
    const float* wgp      = (const float*)d_in[12];

    float* out = (float*)d_out;
    char* ws = (char*)d_ws;
    float* hT   = (float*)(ws + WS_HT);
    unsigned long long* colmin = (unsigned long long*)(ws + WS_COLMIN);
    short8* B2h = (short8*)(ws + WS_B2H);
    short8* B2l = (short8*)(ws + WS_B2L);
    short8* Bhi = (short8*)(ws + WS_BHI);
    short8* Blo = (short8*)(ws + WS_BLO);
    float* part = (float*)(ws + WS_PART);
    const int use_part = (ws_size >= (size_t)WS_PART + PART_BYTES) ? 1 : 0;

    hipMemsetAsync(colmin, 0xFF, BATCH * sizeof(unsigned long long), stream);
    if (!use_part)
        hipMemsetAsync(out + OFF_READ, 0, BATCH * UNITS * sizeof(float), stream);

    k_lstm<<<BATCH / 4, 512, 0, stream>>>(inp, r_tm1, h_tm1, c_tm1, W, RW, bias, out, hT);
    k_hswz<<<16, 256, 0, stream>>>(hT, Bhi, Blo, out + OFF_H, B2h, B2l);
    k_cos_softmax<<<MEM / 64, 256, 0, stream>>>(m_tm1, Bhi, Blo,
                                                cwr_tm1, cwlu_tm1, cwu_tm1, wgp,
                                                out);
    k_colmin<<<MEM / 128, 256, 0, stream>>>(out + OFF_CWU, colmin);
    k_wlu<<<MEM * BATCH / 4096, 256, 0, stream>>>(out + OFF_CWU, colmin, out + OFF_CWLU);
    k_read<<<256, 256, 0, stream>>>(out + OFF_CWR, m_tm1,
                                    use_part ? part : (out + OFF_READ), use_part);
    k_memory<<<MEM / 128, 256, 0, stream>>>(out + OFF_CWW, B2h, B2l, m_tm1, colmin,
                                            part, out + OFF_MEMORY,
                                            out + OFF_READ, use_part);
}

// Round 6
// 456.855 us; speedup vs baseline: 1.1001x; 1.1001x over previous
//
#include <hip/hip_runtime.h>
#include <math.h>

#define MEM 32768
#define UNITS 128
#define BATCH 256
#define IN_DIM 512
#define ZDIM 512      // 4*UNITS
#define CI_DIM 768    // IN_DIM + UNITS(r) + UNITS(h)

// ---- d_out offsets (floats), reference return order ----
#define OFF_READ   0
#define OFF_MEMORY (OFF_READ + BATCH*UNITS)        // 32768
#define OFF_CWU    (OFF_MEMORY + MEM*UNITS)        // 4227072
#define OFF_CWLU   (OFF_CWU + MEM*BATCH)           // 12615680
#define OFF_CWR    (OFF_CWLU + MEM*BATCH)          // 21004288
#define OFF_CWW    (OFF_CWR + MEM*BATCH)           // 29392896
#define OFF_H      (OFF_CWW + MEM*BATCH)           // 37781504
#define OFF_C      (OFF_H + BATCH*UNITS)           // 37814272

// ---- ws offsets (bytes) ----
#define WS_HT     0                                // float[UNITS*BATCH] (scaled h^T)
#define WS_COLMIN (UNITS*BATCH*4)                  // u64[BATCH]          (131072)
#define WS_B2H    (WS_COLMIN + BATCH*8)            // short8 raw-h frags  (133120)
#define WS_B2L    (WS_B2H + 65536)
#define WS_BHI    (WS_B2L + 65536)                 // short8 swizzled hT hi (64 KB)
#define WS_BLO    (WS_BHI + 65536)                 // ends 395264
#define WS_PART   (512*1024)                       // float[64][BATCH][UNITS] split-K partials
#define PART_BYTES (64*BATCH*UNITS*4)              // 8 MB

typedef __attribute__((ext_vector_type(8))) short short8;
typedef __attribute__((ext_vector_type(4))) float f32x4;

__device__ __forceinline__ float sigf(float x) { return 1.0f / (1.0f + __expf(-x)); }
// bf16 round-to-nearest-even from f32 (bits as short)
__device__ __forceinline__ short bf16r(float x) {
    unsigned u = __float_as_uint(x);
    return (short)((u + 0x7fffu + ((u >> 16) & 1u)) >> 16);
}
__device__ __forceinline__ float bf16f(short h) {
    return __uint_as_float(((unsigned)(unsigned short)h) << 16);
}

// ------------------------------------------------------------------
// K1: LSTM cell (4 rows/block), h/c outputs, h-norm, scaled h^T to ws
// ------------------------------------------------------------------
__global__ __launch_bounds__(512) void k_lstm(
    const float* __restrict__ inp, const float* __restrict__ r_tm1,
    const float* __restrict__ h_tm1, const float* __restrict__ c_tm1,
    const float* __restrict__ W, const float* __restrict__ RW,
    const float* __restrict__ bias,
    float* __restrict__ out, float* __restrict__ hT)
{
    __shared__ float ci[4][CI_DIM];
    __shared__ float zl[4][ZDIM];
    __shared__ float part[8];
    const int t = threadIdx.x;
    const int row0 = blockIdx.x * 4;

    for (int i = t; i < 4 * CI_DIM; i += 512) {
        int r = i / CI_DIM, j = i - r * CI_DIM;
        int row = row0 + r;
        float v;
        if (j < IN_DIM)              v = inp[row * IN_DIM + j];
        else if (j < IN_DIM + UNITS) v = r_tm1[row * UNITS + (j - IN_DIM)];
        else                         v = h_tm1[row * UNITS + (j - IN_DIM - UNITS)];
        ci[r][j] = v;
    }
    __syncthreads();

    float b = bias[t];
    float z0 = b, z1 = b, z2 = b, z3 = b;
    for (int k4 = 0; k4 < (IN_DIM + UNITS) / 4; ++k4) {
        float w0 = W[(k4 * 4 + 0) * ZDIM + t];
        float w1 = W[(k4 * 4 + 1) * ZDIM + t];
        float w2 = W[(k4 * 4 + 2) * ZDIM + t];
        float w3 = W[(k4 * 4 + 3) * ZDIM + t];
        float4 a0 = *(const float4*)&ci[0][k4 * 4];
        float4 a1 = *(const float4*)&ci[1][k4 * 4];
        float4 a2 = *(const float4*)&ci[2][k4 * 4];
        float4 a3 = *(const float4*)&ci[3][k4 * 4];
        z0 += a0.x * w0 + a0.y * w1 + a0.z * w2 + a0.w * w3;
        z1 += a1.x * w0 + a1.y * w1 + a1.z * w2 + a1.w * w3;
        z2 += a2.x * w0 + a2.y * w1 + a2.z * w2 + a2.w * w3;
        z3 += a3.x * w0 + a3.y * w1 + a3.z * w2 + a3.w * w3;
    }
    for (int k4 = 0; k4 < UNITS / 4; ++k4) {
        float w0 = RW[(k4 * 4 + 0) * ZDIM + t];
        float w1 = RW[(k4 * 4 + 1) * ZDIM + t];
        float w2 = RW[(k4 * 4 + 2) * ZDIM + t];
        float w3 = RW[(k4 * 4 + 3) * ZDIM + t];
        const int base = IN_DIM + UNITS + k4 * 4;
        float4 a0 = *(const float4*)&ci[0][base];
        float4 a1 = *(const float4*)&ci[1][base];
        float4 a2 = *(const float4*)&ci[2][base];
        float4 a3 = *(const float4*)&ci[3][base];
        z0 += a0.x * w0 + a0.y * w1 + a0.z * w2 + a0.w * w3;
        z1 += a1.x * w0 + a1.y * w1 + a1.z * w2 + a1.w * w3;
        z2 += a2.x * w0 + a2.y * w1 + a2.z * w2 + a2.w * w3;
        z3 += a3.x * w0 + a3.y * w1 + a3.z * w2 + a3.w * w3;
    }
    zl[0][t] = z0; zl[1][t] = z1; zl[2][t] = z2; zl[3][t] = z3;
    __syncthreads();

    const int r = t >> 7, u = t & 127;
    const int row = row0 + r;
    float iv = zl[r][u], fv = zl[r][UNITS + u], gv = zl[r][2 * UNITS + u], ov = zl[r][3 * UNITS + u];
    float ig = sigf(iv), fg = sigf(fv), og = sigf(ov);
    float gt = tanhf(gv);
    float cn = fg * c_tm1[row * UNITS + u] + ig * gt;
    float hn = og * tanhf(cn);
    out[OFF_C + row * UNITS + u] = cn;
    out[OFF_H + row * UNITS + u] = hn;

    float s = hn * hn;
    for (int d = 1; d < 64; d <<= 1) s += __shfl_xor(s, d, 64);
    int wave = t >> 6;
    if ((t & 63) == 0) part[wave] = s;
    __syncthreads();
    float inv = rsqrtf(fmaxf(part[2 * r] + part[2 * r + 1], 1e-12f));
    hT[u * BATCH + row] = hn * inv;
}

// ------------------------------------------------------------------
// K2: swizzle normalized h^T into MFMA layout (bf16 hi/lo), and
// (blocks 0..7) swizzle raw h into K-major MFMA-B fragments for k_memory.
// ------------------------------------------------------------------
__global__ __launch_bounds__(256) void k_hswz(
    const float* __restrict__ hT, short8* __restrict__ Bhi, short8* __restrict__ Blo,
    const float* __restrict__ h, short8* __restrict__ B2h, short8* __restrict__ B2l)
{
    const int t = threadIdx.x, bt = blockIdx.x;
    const int s = t >> 6, L = t & 63;
    const int b = bt * 16 + (L & 15);
    const int k0 = s * 32 + (L >> 4) * 8;
    short8 hi, lo;
#pragma unroll
    for (int j = 0; j < 8; ++j) {
        float x = hT[(k0 + j) * BATCH + b];
        short hb = bf16r(x);
        hi[j] = hb;
        lo[j] = bf16r(x - bf16f(hb));
    }
    Bhi[bt * 256 + t] = hi;
    Blo[bt * 256 + t] = lo;

    if (bt < 8) {  // raw-h fragments (K = batch), block bt covers b-rows bt*32..+31
        const int u = t & 127, op = t >> 7;
#pragma unroll
        for (int oo = 0; oo < 2; ++oo) {
            const int oct = op + 2 * oo;
            short8 h2, l2;
#pragma unroll
            for (int j = 0; j < 8; ++j) {
                float x = h[(bt * 32 + oct * 8 + j) * UNITS + u];
                short hb = bf16r(x);
                h2[j] = hb;
                l2[j] = bf16r(x - bf16f(hb));
            }
            B2h[(bt * 8 + (u >> 4)) * 64 + (u & 15) + 16 * oct] = h2;
            B2l[(bt * 8 + (u >> 4)) * 64 + (u & 15) + 16 * oct] = l2;
        }
    }
}

// ------------------------------------------------------------------
// K3 v7: swapped-operand cos+softmax, batch split across 4 waves.
// Block = 16 memrows (grid 2048). Wave w computes bt = w*4..w*4+3
// (batch w*64..+63) -> acc[4]. Per-wave softmax partials (2 shuffles),
// cross-wave combine via tiny LDS (exact two-level softmax), e-values
// staged in LDS so phase 2 streams fully coalesced (lane = column).
// ------------------------------------------------------------------
__global__ __launch_bounds__(256, 4) void k_cos_softmax(
    const float* __restrict__ m,
    const short8* __restrict__ Bhi, const short8* __restrict__ Blo,
    const float* __restrict__ cwr_tm1, const float* __restrict__ cwlu_tm1,
    const float* __restrict__ cwu_tm1, const float* __restrict__ wgp,
    float* __restrict__ out)
{
    __shared__ float S[16][260];     // staged e-values (16 rows x 256 batch)
    __shared__ float pmx[4][16];     // per-wave row max
    __shared__ float psm[4][16];     // per-wave row sum
    __shared__ float scl[4][16];     // per-wave rescale factor
    const int t = threadIdx.x;
    const int w = t >> 6, L = t & 63;
    const int m0 = blockIdx.x * 16;
    const int row = m0 + (L & 15);   // this lane's memrow (frag role)
    const int q = L >> 4;

    // ---- load this lane's 32 k's of its m row (4 K-steps x 8) ----
    float x[4][8];
#pragma unroll
    for (int s = 0; s < 4; ++s) {
        const float* src = &m[(size_t)row * UNITS + s * 32 + q * 8];
        float4 v0 = *(const float4*)src;
        float4 v1 = *(const float4*)(src + 4);
        x[s][0] = v0.x; x[s][1] = v0.y; x[s][2] = v0.z; x[s][3] = v0.w;
        x[s][4] = v1.x; x[s][5] = v1.y; x[s][6] = v1.z; x[s][7] = v1.w;
    }
    // ---- row L2-norm: in-reg + 2 shuffles across q groups ----
    float ss = 0.f;
#pragma unroll
    for (int s = 0; s < 4; ++s)
#pragma unroll
        for (int j = 0; j < 8; ++j) ss += x[s][j] * x[s][j];
    ss += __shfl_xor(ss, 16, 64);
    ss += __shfl_xor(ss, 32, 64);
    const float inv = rsqrtf(fmaxf(ss, 1e-12f));

    // ---- build mem B-frags (bf16 hi/lo) in registers ----
    short8 mh[4], ml[4];
#pragma unroll
    for (int s = 0; s < 4; ++s) {
#pragma unroll
        for (int j = 0; j < 8; ++j) {
            float xv = x[s][j] * inv;
            short hb = bf16r(xv);
            mh[s][j] = hb;
            ml[s][j] = bf16r(xv - bf16f(hb));
        }
    }

    // ---- MFMA: wave w owns bt = w*4..w*4+3 (batch w*64..+63) ----
    f32x4 acc[4];
#pragma unroll
    for (int i = 0; i < 4; ++i) { acc[i][0] = 0.f; acc[i][1] = 0.f; acc[i][2] = 0.f; acc[i][3] = 0.f; }
#pragma unroll
    for (int i = 0; i < 4; ++i) {
        const int bt = w * 4 + i;
#pragma unroll
        for (int s = 0; s < 4; ++s) {
            short8 kh = Bhi[(bt * 4 + s) * 64 + L];
            short8 kl = Blo[(bt * 4 + s) * 64 + L];
            acc[i] = __builtin_amdgcn_mfma_f32_16x16x32_bf16(kh, mh[s], acc[i], 0, 0, 0);
            acc[i] = __builtin_amdgcn_mfma_f32_16x16x32_bf16(kh, ml[s], acc[i], 0, 0, 0);
            acc[i] = __builtin_amdgcn_mfma_f32_16x16x32_bf16(kl, mh[s], acc[i], 0, 0, 0);
        }
    }

    // ---- per-wave softmax partials for row (L&15) over 64 batch cols ----
    float mx = acc[0][0];
#pragma unroll
    for (int i = 0; i < 4; ++i)
#pragma unroll
        for (int r = 0; r < 4; ++r) mx = fmaxf(mx, acc[i][r]);
    mx = fmaxf(mx, __shfl_xor(mx, 16, 64));
    mx = fmaxf(mx, __shfl_xor(mx, 32, 64));
    float sum = 0.f;
#pragma unroll
    for (int i = 0; i < 4; ++i)
#pragma unroll
        for (int r = 0; r < 4; ++r) {
            float e = __expf(acc[i][r] - mx);
            acc[i][r] = e;
            sum += e;
        }
    sum += __shfl_xor(sum, 16, 64);
    sum += __shfl_xor(sum, 32, 64);

    // ---- stage e-values; publish partials ----
#pragma unroll
    for (int i = 0; i < 4; ++i)
        *(float4*)&S[L & 15][(w * 4 + i) * 16 + q * 4] = *(float4*)&acc[i];
    if (L < 16) { pmx[w][L] = mx; psm[w][L] = sum; }
    __syncthreads();

    if (t < 64) {   // cross-wave combine: scale_v = exp(m_v - M) / S_total
        const int v = t >> 4, i = t & 15;
        float M = fmaxf(fmaxf(pmx[0][i], pmx[1][i]), fmaxf(pmx[2][i], pmx[3][i]));
        float Stot = psm[0][i] * __expf(pmx[0][i] - M) + psm[1][i] * __expf(pmx[1][i] - M)
                   + psm[2][i] * __expf(pmx[2][i] - M) + psm[3][i] * __expf(pmx[3][i] - M);
        scl[v][i] = __expf(pmx[v][i] - M) / Stot;
    }
    __syncthreads();

    // ---- phase 2: coalesced streams; thread t -> row (t>>6), col (t&63)*4
    const float wg = sigf(wgp[0]);
    const float wgc = 1.0f - wg;
    const int c = (t & 63) * 4;
    const int vown = c >> 6;        // staging wave of this column range
#pragma unroll
    for (int ii = 0; ii < 4; ++ii) {
        const int i = ii * 4 + (t >> 6);
        float4 e4 = *(const float4*)&S[i][c];
        const float sc = scl[vown][i];
        float4 wr; wr.x = e4.x * sc; wr.y = e4.y * sc; wr.z = e4.z * sc; wr.w = e4.w * sc;
        const size_t base = (size_t)(m0 + i) * BATCH + c;
        *(float4*)&out[OFF_CWR + base] = wr;

        float4 pr = *(const float4*)&cwr_tm1[base];
        float4 pl = *(const float4*)&cwlu_tm1[base];
        float4 ww;
        ww.x = wg * pr.x + wgc + pl.x; ww.y = wg * pr.y + wgc + pl.y;
        ww.z = wg * pr.z + wgc + pl.z; ww.w = wg * pr.w + wgc + pl.w;
        *(float4*)&out[OFF_CWW + base] = ww;

        float4 pu = *(const float4*)&cwu_tm1[base];
        float4 wu;
        wu.x = 0.95f * pu.x + wr.x + ww.x; wu.y = 0.95f * pu.y + wr.y + ww.y;
        wu.z = 0.95f * pu.z + wr.z + ww.z; wu.w = 0.95f * pu.w + wr.w + ww.w;
        *(float4*)&out[OFF_CWU + base] = wu;
    }
}

// ------------------------------------------------------------------
// K4 v2: per-batch-column min of c_wu (packed key: bits<<32 | MEM-1-row,
// min-key => min value, largest index on ties). 256 blocks x 128 rows.
// ------------------------------------------------------------------
__global__ __launch_bounds__(256) void k_colmin(
    const float* __restrict__ cwu, unsigned long long* __restrict__ colmin)
{
    const int t = threadIdx.x;            // batch column
    const int r0 = blockIdx.x * 128;
    unsigned long long mk = ~0ULL;
    const float* p = &cwu[(size_t)r0 * BATCH + t];
#pragma unroll 4
    for (int i = 0; i < 128; ++i) {
        float v = p[(size_t)i * BATCH];
        unsigned long long k = ((unsigned long long)__float_as_uint(v) << 32)
                             | (unsigned)(MEM - 1 - (r0 + i));
        if (k < mk) mk = k;
    }
    if (mk < colmin[t]) atomicMin(&colmin[t], mk);
}

// ------------------------------------------------------------------
// K5 v2: c_wlu = (c_wu <= minv[b]); minv decoded from colmin in LDS.
// 4 consecutive float4s per thread.
// ------------------------------------------------------------------
__global__ __launch_bounds__(256) void k_wlu(const float* __restrict__ cwu,
                                             const unsigned long long* __restrict__ colmin,
                                             float* __restrict__ wlu)
{
    __shared__ float mvs[256];
    const int t = threadIdx.x;
    mvs[t] = __uint_as_float((unsigned)(colmin[t] >> 32));
    __syncthreads();
    const int i0 = (blockIdx.x * 256 + t) * 4;   // float4 index
#pragma unroll
    for (int j = 0; j < 4; ++j) {
        const int i = i0 + j;
        float4 v = *(const float4*)&cwu[(size_t)i * 4];
        float4 mv = *(const float4*)&mvs[(i & 63) * 4];
        float4 r;
        r.x = (v.x <= mv.x) ? 1.0f : 0.0f;
        r.y = (v.y <= mv.y) ? 1.0f : 0.0f;
        r.z = (v.z <= mv.z) ? 1.0f : 0.0f;
        r.w = (v.w <= mv.w) ? 1.0f : 0.0f;
        *(float4*)&wlu[(size_t)i * 4] = r;
    }
}

// ------------------------------------------------------------------
// K7 v3: read = c_wr^T @ m via MFMA bf16 hi/lo split, split-K.
// ------------------------------------------------------------------
__global__ __launch_bounds__(256) void k_read(
    const float* __restrict__ cwr, const float* __restrict__ m,
    float* __restrict__ dst, int use_part)
{
    __shared__ short8 Ah[4 * 64], Al[4 * 64];
    __shared__ short8 Bh[8 * 64], Bl[8 * 64];
    const int t = threadIdx.x;
    const int w = t >> 6, L = t & 63;
    const int kc = blockIdx.x >> 2;
    const int bq = blockIdx.x & 3;
    const int k0 = kc * 512;

    const int ab = t & 63;           // b within quarter (A staging role)
    const int aoct = t >> 6;         // 0..3
    const int bu = t & 127;          // u (B staging role)
    const int bop = t >> 7;          // 0..1

    f32x4 zero = {0.f, 0.f, 0.f, 0.f};
    f32x4 acc[8];
#pragma unroll
    for (int i = 0; i < 8; ++i) acc[i] = zero;

    float axr[8];
    float bxr[2][8];
#pragma unroll
    for (int j = 0; j < 8; ++j)
        axr[j] = cwr[(size_t)(k0 + aoct * 8 + j) * BATCH + bq * 64 + ab];
#pragma unroll
    for (int oo = 0; oo < 2; ++oo)
#pragma unroll
        for (int j = 0; j < 8; ++j)
            bxr[oo][j] = m[(size_t)(k0 + (bop + 2 * oo) * 8 + j) * UNITS + bu];

    for (int ks = 0; ks < 16; ++ks) {
        {   // convert & store fragments
            short8 hi, lo;
#pragma unroll
            for (int j = 0; j < 8; ++j) {
                short hb = bf16r(axr[j]);
                hi[j] = hb;
                lo[j] = bf16r(axr[j] - bf16f(hb));
            }
            Ah[(ab >> 4) * 64 + (ab & 15) + 16 * aoct] = hi;
            Al[(ab >> 4) * 64 + (ab & 15) + 16 * aoct] = lo;
#pragma unroll
            for (int oo = 0; oo < 2; ++oo) {
                short8 h2, l2;
#pragma unroll
                for (int j = 0; j < 8; ++j) {
                    short hb = bf16r(bxr[oo][j]);
                    h2[j] = hb;
                    l2[j] = bf16r(bxr[oo][j] - bf16f(hb));
                }
                Bh[(bu >> 4) * 64 + (bu & 15) + 16 * (bop + 2 * oo)] = h2;
                Bl[(bu >> 4) * 64 + (bu & 15) + 16 * (bop + 2 * oo)] = l2;
            }
        }
        __syncthreads();
        if (ks < 15) {  // prefetch next tiles under the MFMA phase
            const int kb = k0 + (ks + 1) * 32;
#pragma unroll
            for (int j = 0; j < 8; ++j)
                axr[j] = cwr[(size_t)(kb + aoct * 8 + j) * BATCH + bq * 64 + ab];
#pragma unroll
            for (int oo = 0; oo < 2; ++oo)
#pragma unroll
                for (int j = 0; j < 8; ++j)
                    bxr[oo][j] = m[(size_t)(kb + (bop + 2 * oo) * 8 + j) * UNITS + bu];
        }
        short8 a_h = Ah[w * 64 + L], a_l = Al[w * 64 + L];
#pragma unroll
        for (int nt = 0; nt < 8; ++nt) {
            short8 b_h = Bh[nt * 64 + L], b_l = Bl[nt * 64 + L];
            acc[nt] = __builtin_amdgcn_mfma_f32_16x16x32_bf16(a_h, b_h, acc[nt], 0, 0, 0);
            acc[nt] = __builtin_amdgcn_mfma_f32_16x16x32_bf16(a_h, b_l, acc[nt], 0, 0, 0);
            acc[nt] = __builtin_amdgcn_mfma_f32_16x16x32_bf16(a_l, b_h, acc[nt], 0, 0, 0);
        }
        __syncthreads();
    }

    const int rb = bq * 64 + w * 16 + (L >> 4) * 4;
    const int u0 = L & 15;
    if (use_part) {
        float* p = dst + (size_t)kc * (BATCH * UNITS);
#pragma unroll
        for (int nt = 0; nt < 8; ++nt)
#pragma unroll
            for (int r = 0; r < 4; ++r)
                p[(rb + r) * UNITS + nt * 16 + u0] = acc[nt][r];
    } else {
#pragma unroll
        for (int nt = 0; nt < 8; ++nt)
#pragma unroll
            for (int r = 0; r < 4; ++r)
                atomicAdd(&dst[(rb + r) * UNITS + nt * 16 + u0], acc[nt][r]);
    }
}

// ------------------------------------------------------------------
// K6 v4: memory = c_ww @ h + (BATCH - count)*m, MFMA bf16 hi/lo split.
// Fused: per-block argmin counts decoded from colmin (LDS), and the
// split-K 'read' reduction (block owns slice [bid*128, +128)).
// ------------------------------------------------------------------
__global__ __launch_bounds__(256) void k_memory(
    const float* __restrict__ cww, const short8* __restrict__ B2h,
    const short8* __restrict__ B2l, const float* __restrict__ m,
    const unsigned long long* __restrict__ colmin,
    const float* __restrict__ part, float* __restrict__ mem_out,
    float* __restrict__ read_out, int use_part)
{
    __shared__ short8 Ah[8 * 64], Al[8 * 64];
    __shared__ int cnt[128];
    const int t = threadIdx.x;
    const int w = t >> 6, L = t & 63;
    const int m0 = blockIdx.x * 128;
    const int mr = t & 127;          // m-row within block (A staging role)
    const int op = t >> 7;           // octet pair selector

    if (t < 128) cnt[t] = 0;
    __syncthreads();
    {   // count argmins falling in this block's row range
        unsigned long long k = colmin[t];
        int idx = MEM - 1 - (int)(unsigned)(k & 0xffffffffu);
        unsigned rel = (unsigned)(idx - m0);
        if (rel < 128u) atomicAdd(&cnt[rel], 1);
    }
    if (use_part && t < 128) {   // fused split-K reduce for 'read'
        const int slice = blockIdx.x * 128;
        float s = 0.f;
#pragma unroll
        for (int c = 0; c < 64; ++c) s += part[c * (BATCH * UNITS) + slice + t];
        read_out[slice + t] = s;
    }

    f32x4 zero = {0.f, 0.f, 0.f, 0.f};
    f32x4 acc[2][8];
#pragma unroll
    for (int mi = 0; mi < 2; ++mi)
#pragma unroll
        for (int nt = 0; nt < 8; ++nt) acc[mi][nt] = zero;

    // prefetch A tile for ks=0: cww[m0+mr][oct*8 .. +8]
    float ax[2][8];
#pragma unroll
    for (int oo = 0; oo < 2; ++oo) {
        const float* src = &cww[(size_t)(m0 + mr) * BATCH + (op + 2 * oo) * 8];
        float4 v0 = *(const float4*)src;
        float4 v1 = *(const float4*)(src + 4);
        ax[oo][0] = v0.x; ax[oo][1] = v0.y; ax[oo][2] = v0.z; ax[oo][3] = v0.w;
        ax[oo][4] = v1.x; ax[oo][5] = v1.y; ax[oo][6] = v1.z; ax[oo][7] = v1.w;
    }

    for (int ks = 0; ks < 8; ++ks) {
        // convert & store A fragments
#pragma unroll
        for (int oo = 0; oo < 2; ++oo) {
            const int oct = op + 2 * oo;
            short8 hi, lo;
#pragma unroll
            for (int j = 0; j < 8; ++j) {
                short hb = bf16r(ax[oo][j]);
                hi[j] = hb;
                lo[j] = bf16r(ax[oo][j] - bf16f(hb));
            }
            Ah[(mr >> 4) * 64 + (mr & 15) + 16 * oct] = hi;
            Al[(mr >> 4) * 64 + (mr & 15) + 16 * oct] = lo;
        }
        __syncthreads();
        if (ks < 7) {   // prefetch next A tile under the MFMA phase
#pragma unroll
            for (int oo = 0; oo < 2; ++oo) {
                const float* src = &cww[(size_t)(m0 + mr) * BATCH + (ks + 1) * 32 + (op + 2 * oo) * 8];
                float4 v0 = *(const float4*)src;
                float4 v1 = *(const float4*)(src + 4);
                ax[oo][0] = v0.x; ax[oo][1] = v0.y; ax[oo][2] = v0.z; ax[oo][3] = v0.w;
                ax[oo][4] = v1.x; ax[oo][5] = v1.y; ax[oo][6] = v1.z; ax[oo][7] = v1.w;
            }
        }
        short8 a_h0 = Ah[(2 * w) * 64 + L],     a_l0 = Al[(2 * w) * 64 + L];
        short8 a_h1 = Ah[(2 * w + 1) * 64 + L], a_l1 = Al[(2 * w + 1) * 64 + L];
#pragma unroll
        for (int nt = 0; nt < 8; ++nt) {
            short8 b_h = B2h[(ks * 8 + nt) * 64 + L];
            short8 b_l = B2l[(ks * 8 + nt) * 64 + L];
            acc[0][nt] = __builtin_amdgcn_mfma_f32_16x16x32_bf16(a_h0, b_h, acc[0][nt], 0, 0, 0);
            acc[0][nt] = __builtin_amdgcn_mfma_f32_16x16x32_bf16(a_h0, b_l, acc[0][nt], 0, 0, 0);
            acc[0][nt] = __builtin_amdgcn_mfma_f32_16x16x32_bf16(a_l0, b_h, acc[0][nt], 0, 0, 0);
            acc[1][nt] = __builtin_amdgcn_mfma_f32_16x16x32_bf16(a_h1, b_h, acc[1][nt], 0, 0, 0);
            acc[1][nt] = __builtin_amdgcn_mfma_f32_16x16x32_bf16(a_h1, b_l, acc[1][nt], 0, 0, 0);
            acc[1][nt] = __builtin_amdgcn_mfma_f32_16x16x32_bf16(a_l1, b_h, acc[1][nt], 0, 0, 0);
        }
        __syncthreads();
    }

    // epilogue: C row = mt*16 + (L>>4)*4 + r, col = nt*16 + (L&15)
#pragma unroll
    for (int mi = 0; mi < 2; ++mi) {
#pragma unroll
        for (int r = 0; r < 4; ++r) {
            const int rl = (2 * w + mi) * 16 + (L >> 4) * 4 + r;
            const int row = m0 + rl;
            const float sc = (float)(BATCH - cnt[rl]);
#pragma unroll
            for (int nt = 0; nt < 8; ++nt) {
                const int u = nt * 16 + (L & 15);
                mem_out[row * UNITS + u] = acc[mi][nt][r] + sc * m[row * UNITS + u];
            }
        }
    }
}

// ------------------------------------------------------------------
extern "C" void kernel_launch(void* const* d_in, const int* in_sizes, int n_in,
                              void* d_out, int out_size, void* d_ws, size_t ws_size,
                              hipStream_t stream)
{
    (void)in_sizes; (void)n_in; (void)out_size;
    const float* inp      = (const float*)d_in[0];
    const float* r_tm1    = (const float*)d_in[1];
    const float* m_tm1    = (const float*)d_in[2];
    const float* cwu_tm1  = (const float*)d_in[3];
    const float* cwlu_tm1 = (const float*)d_in[4];
    const float* cwr_tm1  = (const float*)d_in[5];
    // d_in[6] = c_ww_tm1: unused by the reference
    const float* h_tm1    = (const float*)d_in[7];
    const float* c_tm1    = (const float*)d_in[8];
    const float* W        = (const float*)d_in[9];
    const float* RW       = (const float*)d_in[10];
    const float* bias     = (const float*)d_in[11];
    const float* wgp      = (const float*)d_in[12];

    float* out = (float*)d_out;
    char* ws = (char*)d_ws;
    float* hT   = (float*)(ws + WS_HT);
    unsigned long long* colmin = (unsigned long long*)(ws + WS_COLMIN);
    short8* B2h = (short8*)(ws + WS_B2H);
    short8* B2l = (short8*)(ws + WS_B2L);
    short8* Bhi = (short8*)(ws + WS_BHI);
    short8* Blo = (short8*)(ws + WS_BLO);
    float* part = (float*)(ws + WS_PART);
    const int use_part = (ws_size >= (size_t)WS_PART + PART_BYTES) ? 1 : 0;

    hipMemsetAsync(colmin, 0xFF, BATCH * sizeof(unsigned long long), stream);
    if (!use_part)
        hipMemsetAsync(out + OFF_READ, 0, BATCH * UNITS * sizeof(float), stream);

    k_lstm<<<BATCH / 4, 512, 0, stream>>>(inp, r_tm1, h_tm1, c_tm1, W, RW, bias, out, hT);
    k_hswz<<<16, 256, 0, stream>>>(hT, Bhi, Blo, out + OFF_H, B2h, B2l);
    k_cos_softmax<<<MEM / 16, 256, 0, stream>>>(m_tm1, Bhi, Blo,
                                                cwr_tm1, cwlu_tm1, cwu_tm1, wgp,
                                                out);
    k_colmin<<<MEM / 128, 256, 0, stream>>>(out + OFF_CWU, colmin);
    k_wlu<<<MEM * BATCH / 4096, 256, 0, stream>>>(out + OFF_CWU, colmin, out + OFF_CWLU);
    k_read<<<256, 256, 0, stream>>>(out + OFF_CWR, m_tm1,
                                    use_part ? part : (out + OFF_READ), use_part);
    k_memory<<<MEM / 128, 256, 0, stream>>>(out + OFF_CWW, B2h, B2l, m_tm1, colmin,
                                            part, out + OFF_MEMORY,
                                            out + OFF_READ, use_part);
}

// Round 7
// 437.337 us; speedup vs baseline: 1.1492x; 1.0446x over previous
//
#include <hip/hip_runtime.h>
#include <math.h>

#define MEM 32768
#define UNITS 128
#define BATCH 256
#define IN_DIM 512
#define ZDIM 512      // 4*UNITS
#define CI_DIM 768    // IN_DIM + UNITS(r) + UNITS(h)

// ---- d_out offsets (floats), reference return order ----
#define OFF_READ   0
#define OFF_MEMORY (OFF_READ + BATCH*UNITS)        // 32768
#define OFF_CWU    (OFF_MEMORY + MEM*UNITS)        // 4227072
#define OFF_CWLU   (OFF_CWU + MEM*BATCH)           // 12615680
#define OFF_CWR    (OFF_CWLU + MEM*BATCH)          // 21004288
#define OFF_CWW    (OFF_CWR + MEM*BATCH)           // 29392896
#define OFF_H      (OFF_CWW + MEM*BATCH)           // 37781504
#define OFF_C      (OFF_H + BATCH*UNITS)           // 37814272

// ---- ws offsets (bytes) ----
#define WS_HT     0                                // float[UNITS*BATCH] (scaled h^T)
#define WS_COLMIN (UNITS*BATCH*4)                  // u64[BATCH]          (131072)
#define WS_B2H    (WS_COLMIN + BATCH*8)            // short8 raw-h frags  (133120)
#define WS_B2L    (WS_B2H + 65536)
#define WS_BHI    (WS_B2L + 65536)                 // short8 swizzled hT hi (64 KB)
#define WS_BLO    (WS_BHI + 65536)                 // ends 395264
#define WS_PART   (512*1024)                       // float[64][BATCH][UNITS] split-K partials
#define PART_BYTES (64*BATCH*UNITS*4)              // 8 MB

typedef __attribute__((ext_vector_type(8))) short short8;
typedef __attribute__((ext_vector_type(4))) float f32x4;

__device__ __forceinline__ float sigf(float x) { return 1.0f / (1.0f + __expf(-x)); }
// bf16 round-to-nearest-even from f32 (bits as short)
__device__ __forceinline__ short bf16r(float x) {
    unsigned u = __float_as_uint(x);
    return (short)((u + 0x7fffu + ((u >> 16) & 1u)) >> 16);
}
__device__ __forceinline__ float bf16f(short h) {
    return __uint_as_float(((unsigned)(unsigned short)h) << 16);
}

// ------------------------------------------------------------------
// K1: LSTM cell (4 rows/block), h/c outputs, h-norm, scaled h^T to ws
// ------------------------------------------------------------------
__global__ __launch_bounds__(512) void k_lstm(
    const float* __restrict__ inp, const float* __restrict__ r_tm1,
    const float* __restrict__ h_tm1, const float* __restrict__ c_tm1,
    const float* __restrict__ W, const float* __restrict__ RW,
    const float* __restrict__ bias,
    float* __restrict__ out, float* __restrict__ hT)
{
    __shared__ float ci[4][CI_DIM];
    __shared__ float zl[4][ZDIM];
    __shared__ float part[8];
    const int t = threadIdx.x;
    const int row0 = blockIdx.x * 4;

    for (int i = t; i < 4 * CI_DIM; i += 512) {
        int r = i / CI_DIM, j = i - r * CI_DIM;
        int row = row0 + r;
        float v;
        if (j < IN_DIM)              v = inp[row * IN_DIM + j];
        else if (j < IN_DIM + UNITS) v = r_tm1[row * UNITS + (j - IN_DIM)];
        else                         v = h_tm1[row * UNITS + (j - IN_DIM - UNITS)];
        ci[r][j] = v;
    }
    __syncthreads();

    float b = bias[t];
    float z0 = b, z1 = b, z2 = b, z3 = b;
    for (int k4 = 0; k4 < (IN_DIM + UNITS) / 4; ++k4) {
        float w0 = W[(k4 * 4 + 0) * ZDIM + t];
        float w1 = W[(k4 * 4 + 1) * ZDIM + t];
        float w2 = W[(k4 * 4 + 2) * ZDIM + t];
        float w3 = W[(k4 * 4 + 3) * ZDIM + t];
        float4 a0 = *(const float4*)&ci[0][k4 * 4];
        float4 a1 = *(const float4*)&ci[1][k4 * 4];
        float4 a2 = *(const float4*)&ci[2][k4 * 4];
        float4 a3 = *(const float4*)&ci[3][k4 * 4];
        z0 += a0.x * w0 + a0.y * w1 + a0.z * w2 + a0.w * w3;
        z1 += a1.x * w0 + a1.y * w1 + a1.z * w2 + a1.w * w3;
        z2 += a2.x * w0 + a2.y * w1 + a2.z * w2 + a2.w * w3;
        z3 += a3.x * w0 + a3.y * w1 + a3.z * w2 + a3.w * w3;
    }
    for (int k4 = 0; k4 < UNITS / 4; ++k4) {
        float w0 = RW[(k4 * 4 + 0) * ZDIM + t];
        float w1 = RW[(k4 * 4 + 1) * ZDIM + t];
        float w2 = RW[(k4 * 4 + 2) * ZDIM + t];
        float w3 = RW[(k4 * 4 + 3) * ZDIM + t];
        const int base = IN_DIM + UNITS + k4 * 4;
        float4 a0 = *(const float4*)&ci[0][base];
        float4 a1 = *(const float4*)&ci[1][base];
        float4 a2 = *(const float4*)&ci[2][base];
        float4 a3 = *(const float4*)&ci[3][base];
        z0 += a0.x * w0 + a0.y * w1 + a0.z * w2 + a0.w * w3;
        z1 += a1.x * w0 + a1.y * w1 + a1.z * w2 + a1.w * w3;
        z2 += a2.x * w0 + a2.y * w1 + a2.z * w2 + a2.w * w3;
        z3 += a3.x * w0 + a3.y * w1 + a3.z * w2 + a3.w * w3;
    }
    zl[0][t] = z0; zl[1][t] = z1; zl[2][t] = z2; zl[3][t] = z3;
    __syncthreads();

    const int r = t >> 7, u = t & 127;
    const int row = row0 + r;
    float iv = zl[r][u], fv = zl[r][UNITS + u], gv = zl[r][2 * UNITS + u], ov = zl[r][3 * UNITS + u];
    float ig = sigf(iv), fg = sigf(fv), og = sigf(ov);
    float gt = tanhf(gv);
    float cn = fg * c_tm1[row * UNITS + u] + ig * gt;
    float hn = og * tanhf(cn);
    out[OFF_C + row * UNITS + u] = cn;
    out[OFF_H + row * UNITS + u] = hn;

    float s = hn * hn;
    for (int d = 1; d < 64; d <<= 1) s += __shfl_xor(s, d, 64);
    int wave = t >> 6;
    if ((t & 63) == 0) part[wave] = s;
    __syncthreads();
    float inv = rsqrtf(fmaxf(part[2 * r] + part[2 * r + 1], 1e-12f));
    hT[u * BATCH + row] = hn * inv;
}

// ------------------------------------------------------------------
// K2: swizzle normalized h^T into MFMA layout (bf16 hi/lo), and
// (blocks 0..7) swizzle raw h into K-major MFMA-B fragments for k_memory.
// ------------------------------------------------------------------
__global__ __launch_bounds__(256) void k_hswz(
    const float* __restrict__ hT, short8* __restrict__ Bhi, short8* __restrict__ Blo,
    const float* __restrict__ h, short8* __restrict__ B2h, short8* __restrict__ B2l)
{
    const int t = threadIdx.x, bt = blockIdx.x;
    const int s = t >> 6, L = t & 63;
    const int b = bt * 16 + (L & 15);
    const int k0 = s * 32 + (L >> 4) * 8;
    short8 hi, lo;
#pragma unroll
    for (int j = 0; j < 8; ++j) {
        float x = hT[(k0 + j) * BATCH + b];
        short hb = bf16r(x);
        hi[j] = hb;
        lo[j] = bf16r(x - bf16f(hb));
    }
    Bhi[bt * 256 + t] = hi;
    Blo[bt * 256 + t] = lo;

    if (bt < 8) {  // raw-h fragments (K = batch), block bt covers b-rows bt*32..+31
        const int u = t & 127, op = t >> 7;
#pragma unroll
        for (int oo = 0; oo < 2; ++oo) {
            const int oct = op + 2 * oo;
            short8 h2, l2;
#pragma unroll
            for (int j = 0; j < 8; ++j) {
                float x = h[(bt * 32 + oct * 8 + j) * UNITS + u];
                short hb = bf16r(x);
                h2[j] = hb;
                l2[j] = bf16r(x - bf16f(hb));
            }
            B2h[(bt * 8 + (u >> 4)) * 64 + (u & 15) + 16 * oct] = h2;
            B2l[(bt * 8 + (u >> 4)) * 64 + (u & 15) + 16 * oct] = l2;
        }
    }
}

// ------------------------------------------------------------------
// K3 v8: v7 + fused column-min (kills k_colmin and its 33.5 MB re-read).
// Swapped-operand cos+softmax, batch split across 4 waves, 16 memrows/
// block (grid 2048). Phase 2 threads hold wu for 4 cols x 4 rows ->
// per-block column min via LDS combine (reusing S), peeked atomicMin.
// Packing (bits<<32 | MEM-1-row): min-key = min value, largest row on
// ties — matches top_k's nth-element semantics (validated in k_colmin).
// ------------------------------------------------------------------
__global__ __launch_bounds__(256, 4) void k_cos_softmax(
    const float* __restrict__ m,
    const short8* __restrict__ Bhi, const short8* __restrict__ Blo,
    const float* __restrict__ cwr_tm1, const float* __restrict__ cwlu_tm1,
    const float* __restrict__ cwu_tm1, const float* __restrict__ wgp,
    float* __restrict__ out, unsigned long long* __restrict__ colmin)
{
    __shared__ float S[16][260];     // staged e-values; reused as u64 wmin[4][256]
    __shared__ float pmx[4][16];     // per-wave row max
    __shared__ float psm[4][16];     // per-wave row sum
    __shared__ float scl[4][16];     // per-wave rescale factor
    const int t = threadIdx.x;
    const int w = t >> 6, L = t & 63;
    const int m0 = blockIdx.x * 16;
    const int row = m0 + (L & 15);   // this lane's memrow (frag role)
    const int q = L >> 4;

    // ---- load this lane's 32 k's of its m row (4 K-steps x 8) ----
    float x[4][8];
#pragma unroll
    for (int s = 0; s < 4; ++s) {
        const float* src = &m[(size_t)row * UNITS + s * 32 + q * 8];
        float4 v0 = *(const float4*)src;
        float4 v1 = *(const float4*)(src + 4);
        x[s][0] = v0.x; x[s][1] = v0.y; x[s][2] = v0.z; x[s][3] = v0.w;
        x[s][4] = v1.x; x[s][5] = v1.y; x[s][6] = v1.z; x[s][7] = v1.w;
    }
    // ---- row L2-norm: in-reg + 2 shuffles across q groups ----
    float ss = 0.f;
#pragma unroll
    for (int s = 0; s < 4; ++s)
#pragma unroll
        for (int j = 0; j < 8; ++j) ss += x[s][j] * x[s][j];
    ss += __shfl_xor(ss, 16, 64);
    ss += __shfl_xor(ss, 32, 64);
    const float inv = rsqrtf(fmaxf(ss, 1e-12f));

    // ---- build mem B-frags (bf16 hi/lo) in registers ----
    short8 mh[4], ml[4];
#pragma unroll
    for (int s = 0; s < 4; ++s) {
#pragma unroll
        for (int j = 0; j < 8; ++j) {
            float xv = x[s][j] * inv;
            short hb = bf16r(xv);
            mh[s][j] = hb;
            ml[s][j] = bf16r(xv - bf16f(hb));
        }
    }

    // ---- MFMA: wave w owns bt = w*4..w*4+3 (batch w*64..+63) ----
    f32x4 acc[4];
#pragma unroll
    for (int i = 0; i < 4; ++i) { acc[i][0] = 0.f; acc[i][1] = 0.f; acc[i][2] = 0.f; acc[i][3] = 0.f; }
#pragma unroll
    for (int i = 0; i < 4; ++i) {
        const int bt = w * 4 + i;
#pragma unroll
        for (int s = 0; s < 4; ++s) {
            short8 kh = Bhi[(bt * 4 + s) * 64 + L];
            short8 kl = Blo[(bt * 4 + s) * 64 + L];
            acc[i] = __builtin_amdgcn_mfma_f32_16x16x32_bf16(kh, mh[s], acc[i], 0, 0, 0);
            acc[i] = __builtin_amdgcn_mfma_f32_16x16x32_bf16(kh, ml[s], acc[i], 0, 0, 0);
            acc[i] = __builtin_amdgcn_mfma_f32_16x16x32_bf16(kl, mh[s], acc[i], 0, 0, 0);
        }
    }

    // ---- per-wave softmax partials for row (L&15) over 64 batch cols ----
    float mx = acc[0][0];
#pragma unroll
    for (int i = 0; i < 4; ++i)
#pragma unroll
        for (int r = 0; r < 4; ++r) mx = fmaxf(mx, acc[i][r]);
    mx = fmaxf(mx, __shfl_xor(mx, 16, 64));
    mx = fmaxf(mx, __shfl_xor(mx, 32, 64));
    float sum = 0.f;
#pragma unroll
    for (int i = 0; i < 4; ++i)
#pragma unroll
        for (int r = 0; r < 4; ++r) {
            float e = __expf(acc[i][r] - mx);
            acc[i][r] = e;
            sum += e;
        }
    sum += __shfl_xor(sum, 16, 64);
    sum += __shfl_xor(sum, 32, 64);

    // ---- stage e-values; publish partials ----
#pragma unroll
    for (int i = 0; i < 4; ++i)
        *(float4*)&S[L & 15][(w * 4 + i) * 16 + q * 4] = *(float4*)&acc[i];
    if (L < 16) { pmx[w][L] = mx; psm[w][L] = sum; }
    __syncthreads();

    if (t < 64) {   // cross-wave combine: scale_v = exp(m_v - M) / S_total
        const int v = t >> 4, i = t & 15;
        float M = fmaxf(fmaxf(pmx[0][i], pmx[1][i]), fmaxf(pmx[2][i], pmx[3][i]));
        float Stot = psm[0][i] * __expf(pmx[0][i] - M) + psm[1][i] * __expf(pmx[1][i] - M)
                   + psm[2][i] * __expf(pmx[2][i] - M) + psm[3][i] * __expf(pmx[3][i] - M);
        scl[v][i] = __expf(pmx[v][i] - M) / Stot;
    }
    __syncthreads();

    // ---- phase 2: coalesced streams; thread t -> rows {rg,4+rg,8+rg,12+rg}
    //      (rg = t>>6), cols c..c+3 (c = (t&63)*4). Column-min keys kept
    //      in registers for the fused colmin epilogue.
    const float wg = sigf(wgp[0]);
    const float wgc = 1.0f - wg;
    const int c = (t & 63) * 4;
    const int vown = c >> 6;        // staging wave of this column range
    unsigned long long mk0 = ~0ULL, mk1 = ~0ULL, mk2 = ~0ULL, mk3 = ~0ULL;
#pragma unroll
    for (int ii = 0; ii < 4; ++ii) {
        const int i = ii * 4 + (t >> 6);
        float4 e4 = *(const float4*)&S[i][c];
        const float sc = scl[vown][i];
        float4 wr; wr.x = e4.x * sc; wr.y = e4.y * sc; wr.z = e4.z * sc; wr.w = e4.w * sc;
        const size_t base = (size_t)(m0 + i) * BATCH + c;
        *(float4*)&out[OFF_CWR + base] = wr;

        float4 pr = *(const float4*)&cwr_tm1[base];
        float4 pl = *(const float4*)&cwlu_tm1[base];
        float4 ww;
        ww.x = wg * pr.x + wgc + pl.x; ww.y = wg * pr.y + wgc + pl.y;
        ww.z = wg * pr.z + wgc + pl.z; ww.w = wg * pr.w + wgc + pl.w;
        *(float4*)&out[OFF_CWW + base] = ww;

        float4 pu = *(const float4*)&cwu_tm1[base];
        float4 wu;
        wu.x = 0.95f * pu.x + wr.x + ww.x; wu.y = 0.95f * pu.y + wr.y + ww.y;
        wu.z = 0.95f * pu.z + wr.z + ww.z; wu.w = 0.95f * pu.w + wr.w + ww.w;
        *(float4*)&out[OFF_CWU + base] = wu;

        // pack (bits<<32)|(MEM-1-row): min-key => min value, largest row on ties
        const unsigned idxc = (unsigned)(MEM - 1 - (m0 + i));
        unsigned long long k;
        k = ((unsigned long long)__float_as_uint(wu.x) << 32) | idxc; if (k < mk0) mk0 = k;
        k = ((unsigned long long)__float_as_uint(wu.y) << 32) | idxc; if (k < mk1) mk1 = k;
        k = ((unsigned long long)__float_as_uint(wu.z) << 32) | idxc; if (k < mk2) mk2 = k;
        k = ((unsigned long long)__float_as_uint(wu.w) << 32) | idxc; if (k < mk3) mk3 = k;
    }

    // ---- fused colmin: combine the 4 row-groups per column, one peeked
    //      atomicMin per column per block. Reuses S (8 KB of 16.6 KB).
    __syncthreads();   // all S reads in phase 2 complete
    unsigned long long* wmin = (unsigned long long*)S;
    const int rg = t >> 6;
    wmin[rg * 256 + c + 0] = mk0;
    wmin[rg * 256 + c + 1] = mk1;
    wmin[rg * 256 + c + 2] = mk2;
    wmin[rg * 256 + c + 3] = mk3;
    __syncthreads();
    {
        unsigned long long a = wmin[t];
        unsigned long long b2 = wmin[256 + t];
        unsigned long long c2 = wmin[512 + t];
        unsigned long long d2 = wmin[768 + t];
        unsigned long long k = a < b2 ? a : b2;
        if (c2 < k) k = c2;
        if (d2 < k) k = d2;
        if (k < colmin[t]) atomicMin(&colmin[t], k);   // peek: monotone-safe
    }
}

// ------------------------------------------------------------------
// K5 v2: c_wlu = (c_wu <= minv[b]); minv decoded from colmin in LDS.
// 4 consecutive float4s per thread.
// ------------------------------------------------------------------
__global__ __launch_bounds__(256) void k_wlu(const float* __restrict__ cwu,
                                             const unsigned long long* __restrict__ colmin,
                                             float* __restrict__ wlu)
{
    __shared__ float mvs[256];
    const int t = threadIdx.x;
    mvs[t] = __uint_as_float((unsigned)(colmin[t] >> 32));
    __syncthreads();
    const int i0 = (blockIdx.x * 256 + t) * 4;   // float4 index
#pragma unroll
    for (int j = 0; j < 4; ++j) {
        const int i = i0 + j;
        float4 v = *(const float4*)&cwu[(size_t)i * 4];
        float4 mv = *(const float4*)&mvs[(i & 63) * 4];
        float4 r;
        r.x = (v.x <= mv.x) ? 1.0f : 0.0f;
        r.y = (v.y <= mv.y) ? 1.0f : 0.0f;
        r.z = (v.z <= mv.z) ? 1.0f : 0.0f;
        r.w = (v.w <= mv.w) ? 1.0f : 0.0f;
        *(float4*)&wlu[(size_t)i * 4] = r;
    }
}

// ------------------------------------------------------------------
// K7 v3: read = c_wr^T @ m via MFMA bf16 hi/lo split, split-K.
// ------------------------------------------------------------------
__global__ __launch_bounds__(256) void k_read(
    const float* __restrict__ cwr, const float* __restrict__ m,
    float* __restrict__ dst, int use_part)
{
    __shared__ short8 Ah[4 * 64], Al[4 * 64];
    __shared__ short8 Bh[8 * 64], Bl[8 * 64];
    const int t = threadIdx.x;
    const int w = t >> 6, L = t & 63;
    const int kc = blockIdx.x >> 2;
    const int bq = blockIdx.x & 3;
    const int k0 = kc * 512;

    const int ab = t & 63;           // b within quarter (A staging role)
    const int aoct = t >> 6;         // 0..3
    const int bu = t & 127;          // u (B staging role)
    const int bop = t >> 7;          // 0..1

    f32x4 zero = {0.f, 0.f, 0.f, 0.f};
    f32x4 acc[8];
#pragma unroll
    for (int i = 0; i < 8; ++i) acc[i] = zero;

    float axr[8];
    float bxr[2][8];
#pragma unroll
    for (int j = 0; j < 8; ++j)
        axr[j] = cwr[(size_t)(k0 + aoct * 8 + j) * BATCH + bq * 64 + ab];
#pragma unroll
    for (int oo = 0; oo < 2; ++oo)
#pragma unroll
        for (int j = 0; j < 8; ++j)
            bxr[oo][j] = m[(size_t)(k0 + (bop + 2 * oo) * 8 + j) * UNITS + bu];

    for (int ks = 0; ks < 16; ++ks) {
        {   // convert & store fragments
            short8 hi, lo;
#pragma unroll
            for (int j = 0; j < 8; ++j) {
                short hb = bf16r(axr[j]);
                hi[j] = hb;
                lo[j] = bf16r(axr[j] - bf16f(hb));
            }
            Ah[(ab >> 4) * 64 + (ab & 15) + 16 * aoct] = hi;
            Al[(ab >> 4) * 64 + (ab & 15) + 16 * aoct] = lo;
#pragma unroll
            for (int oo = 0; oo < 2; ++oo) {
                short8 h2, l2;
#pragma unroll
                for (int j = 0; j < 8; ++j) {
                    short hb = bf16r(bxr[oo][j]);
                    h2[j] = hb;
                    l2[j] = bf16r(bxr[oo][j] - bf16f(hb));
                }
                Bh[(bu >> 4) * 64 + (bu & 15) + 16 * (bop + 2 * oo)] = h2;
                Bl[(bu >> 4) * 64 + (bu & 15) + 16 * (bop + 2 * oo)] = l2;
            }
        }
        __syncthreads();
        if (ks < 15) {  // prefetch next tiles under the MFMA phase
            const int kb = k0 + (ks + 1) * 32;
#pragma unroll
            for (int j = 0; j < 8; ++j)
                axr[j] = cwr[(size_t)(kb + aoct * 8 + j) * BATCH + bq * 64 + ab];
#pragma unroll
            for (int oo = 0; oo < 2; ++oo)
#pragma unroll
                for (int j = 0; j < 8; ++j)
                    bxr[oo][j] = m[(size_t)(kb + (bop + 2 * oo) * 8 + j) * UNITS + bu];
        }
        short8 a_h = Ah[w * 64 + L], a_l = Al[w * 64 + L];
#pragma unroll
        for (int nt = 0; nt < 8; ++nt) {
            short8 b_h = Bh[nt * 64 + L], b_l = Bl[nt * 64 + L];
            acc[nt] = __builtin_amdgcn_mfma_f32_16x16x32_bf16(a_h, b_h, acc[nt], 0, 0, 0);
            acc[nt] = __builtin_amdgcn_mfma_f32_16x16x32_bf16(a_h, b_l, acc[nt], 0, 0, 0);
            acc[nt] = __builtin_amdgcn_mfma_f32_16x16x32_bf16(a_l, b_h, acc[nt], 0, 0, 0);
        }
        __syncthreads();
    }

    const int rb = bq * 64 + w * 16 + (L >> 4) * 4;
    const int u0 = L & 15;
    if (use_part) {
        float* p = dst + (size_t)kc * (BATCH * UNITS);
#pragma unroll
        for (int nt = 0; nt < 8; ++nt)
#pragma unroll
            for (int r = 0; r < 4; ++r)
                p[(rb + r) * UNITS + nt * 16 + u0] = acc[nt][r];
    } else {
#pragma unroll
        for (int nt = 0; nt < 8; ++nt)
#pragma unroll
            for (int r = 0; r < 4; ++r)
                atomicAdd(&dst[(rb + r) * UNITS + nt * 16 + u0], acc[nt][r]);
    }
}

// ------------------------------------------------------------------
// K6 v4: memory = c_ww @ h + (BATCH - count)*m, MFMA bf16 hi/lo split.
// Fused: per-block argmin counts decoded from colmin (LDS), and the
// split-K 'read' reduction (block owns slice [bid*128, +128)).
// ------------------------------------------------------------------
__global__ __launch_bounds__(256) void k_memory(
    const float* __restrict__ cww, const short8* __restrict__ B2h,
    const short8* __restrict__ B2l, const float* __restrict__ m,
    const unsigned long long* __restrict__ colmin,
    const float* __restrict__ part, float* __restrict__ mem_out,
    float* __restrict__ read_out, int use_part)
{
    __shared__ short8 Ah[8 * 64], Al[8 * 64];
    __shared__ int cnt[128];
    const int t = threadIdx.x;
    const int w = t >> 6, L = t & 63;
    const int m0 = blockIdx.x * 128;
    const int mr = t & 127;          // m-row within block (A staging role)
    const int op = t >> 7;           // octet pair selector

    if (t < 128) cnt[t] = 0;
    __syncthreads();
    {   // count argmins falling in this block's row range
        unsigned long long k = colmin[t];
        int idx = MEM - 1 - (int)(unsigned)(k & 0xffffffffu);
        unsigned rel = (unsigned)(idx - m0);
        if (rel < 128u) atomicAdd(&cnt[rel], 1);
    }
    if (use_part && t < 128) {   // fused split-K reduce for 'read'
        const int slice = blockIdx.x * 128;
        float s = 0.f;
#pragma unroll
        for (int c = 0; c < 64; ++c) s += part[c * (BATCH * UNITS) + slice + t];
        read_out[slice + t] = s;
    }

    f32x4 zero = {0.f, 0.f, 0.f, 0.f};
    f32x4 acc[2][8];
#pragma unroll
    for (int mi = 0; mi < 2; ++mi)
#pragma unroll
        for (int nt = 0; nt < 8; ++nt) acc[mi][nt] = zero;

    // prefetch A tile for ks=0: cww[m0+mr][oct*8 .. +8]
    float ax[2][8];
#pragma unroll
    for (int oo = 0; oo < 2; ++oo) {
        const float* src = &cww[(size_t)(m0 + mr) * BATCH + (op + 2 * oo) * 8];
        float4 v0 = *(const float4*)src;
        float4 v1 = *(const float4*)(src + 4);
        ax[oo][0] = v0.x; ax[oo][1] = v0.y; ax[oo][2] = v0.z; ax[oo][3] = v0.w;
        ax[oo][4] = v1.x; ax[oo][5] = v1.y; ax[oo][6] = v1.z; ax[oo][7] = v1.w;
    }

    for (int ks = 0; ks < 8; ++ks) {
        // convert & store A fragments
#pragma unroll
        for (int oo = 0; oo < 2; ++oo) {
            const int oct = op + 2 * oo;
            short8 hi, lo;
#pragma unroll
            for (int j = 0; j < 8; ++j) {
                short hb = bf16r(ax[oo][j]);
                hi[j] = hb;
                lo[j] = bf16r(ax[oo][j] - bf16f(hb));
            }
            Ah[(mr >> 4) * 64 + (mr & 15) + 16 * oct] = hi;
            Al[(mr >> 4) * 64 + (mr & 15) + 16 * oct] = lo;
        }
        __syncthreads();
        if (ks < 7) {   // prefetch next A tile under the MFMA phase
#pragma unroll
            for (int oo = 0; oo < 2; ++oo) {
                const float* src = &cww[(size_t)(m0 + mr) * BATCH + (ks + 1) * 32 + (op + 2 * oo) * 8];
                float4 v0 = *(const float4*)src;
                float4 v1 = *(const float4*)(src + 4);
                ax[oo][0] = v0.x; ax[oo][1] = v0.y; ax[oo][2] = v0.z; ax[oo][3] = v0.w;
                ax[oo][4] = v1.x; ax[oo][5] = v1.y; ax[oo][6] = v1.z; ax[oo][7] = v1.w;
            }
        }
        short8 a_h0 = Ah[(2 * w) * 64 + L],     a_l0 = Al[(2 * w) * 64 + L];
        short8 a_h1 = Ah[(2 * w + 1) * 64 + L], a_l1 = Al[(2 * w + 1) * 64 + L];
#pragma unroll
        for (int nt = 0; nt < 8; ++nt) {
            short8 b_h = B2h[(ks * 8 + nt) * 64 + L];
            short8 b_l = B2l[(ks * 8 + nt) * 64 + L];
            acc[0][nt] = __builtin_amdgcn_mfma_f32_16x16x32_bf16(a_h0, b_h, acc[0][nt], 0, 0, 0);
            acc[0][nt] = __builtin_amdgcn_mfma_f32_16x16x32_bf16(a_h0, b_l, acc[0][nt], 0, 0, 0);
            acc[0][nt] = __builtin_amdgcn_mfma_f32_16x16x32_bf16(a_l0, b_h, acc[0][nt], 0, 0, 0);
            acc[1][nt] = __builtin_amdgcn_mfma_f32_16x16x32_bf16(a_h1, b_h, acc[1][nt], 0, 0, 0);
            acc[1][nt] = __builtin_amdgcn_mfma_f32_16x16x32_bf16(a_h1, b_l, acc[1][nt], 0, 0, 0);
            acc[1][nt] = __builtin_amdgcn_mfma_f32_16x16x32_bf16(a_l1, b_h, acc[1][nt], 0, 0, 0);
        }
        __syncthreads();
    }

    // epilogue: C row = mt*16 + (L>>4)*4 + r, col = nt*16 + (L&15)
#pragma unroll
    for (int mi = 0; mi < 2; ++mi) {
#pragma unroll
        for (int r = 0; r < 4; ++r) {
            const int rl = (2 * w + mi) * 16 + (L >> 4) * 4 + r;
            const int row = m0 + rl;
            const float sc = (float)(BATCH - cnt[rl]);
#pragma unroll
            for (int nt = 0; nt < 8; ++nt) {
                const int u = nt * 16 + (L & 15);
                mem_out[row * UNITS + u] = acc[mi][nt][r] + sc * m[row * UNITS + u];
            }
        }
    }
}

// ------------------------------------------------------------------
extern "C" void kernel_launch(void* const* d_in, const int* in_sizes, int n_in,
                              void* d_out, int out_size, void* d_ws, size_t ws_size,
                              hipStream_t stream)
{
    (void)in_sizes; (void)n_in; (void)out_size;
    const float* inp      = (const float*)d_in[0];
    const float* r_tm1    = (const float*)d_in[1];
    const float* m_tm1    = (const float*)d_in[2];
    const float* cwu_tm1  = (const float*)d_in[3];
    const float* cwlu_tm1 = (const float*)d_in[4];
    const float* cwr_tm1  = (const float*)d_in[5];
    // d_in[6] = c_ww_tm1: unused by the reference
    const float* h_tm1    = (const float*)d_in[7];
    const float* c_tm1    = (const float*)d_in[8];
    const float* W        = (const float*)d_in[9];
    const float* RW       = (const float*)d_in[10];
    const float* bias     = (const float*)d_in[11];
    const float* wgp      = (const float*)d_in[12];

    float* out = (float*)d_out;
    char* ws = (char*)d_ws;
    float* hT   = (float*)(ws + WS_HT);
    unsigned long long* colmin = (unsigned long long*)(ws + WS_COLMIN);
    short8* B2h = (short8*)(ws + WS_B2H);
    short8* B2l = (short8*)(ws + WS_B2L);
    short8* Bhi = (short8*)(ws + WS_BHI);
    short8* Blo = (short8*)(ws + WS_BLO);
    float* part = (float*)(ws + WS_PART);
    const int use_part = (ws_size >= (size_t)WS_PART + PART_BYTES) ? 1 : 0;

    hipMemsetAsync(colmin, 0xFF, BATCH * sizeof(unsigned long long), stream);
    if (!use_part)
        hipMemsetAsync(out + OFF_READ, 0, BATCH * UNITS * sizeof(float), stream);

    k_lstm<<<BATCH / 4, 512, 0, stream>>>(inp, r_tm1, h_tm1, c_tm1, W, RW, bias, out, hT);
    k_hswz<<<16, 256, 0, stream>>>(hT, Bhi, Blo, out + OFF_H, B2h, B2l);
    k_cos_softmax<<<MEM / 16, 256, 0, stream>>>(m_tm1, Bhi, Blo,
                                                cwr_tm1, cwlu_tm1, cwu_tm1, wgp,
                                                out, colmin);
    k_wlu<<<MEM * BATCH / 4096, 256, 0, stream>>>(out + OFF_CWU, colmin, out + OFF_CWLU);
    k_read<<<256, 256, 0, stream>>>(out + OFF_CWR, m_tm1,
                                    use_part ? part : (out + OFF_READ), use_part);
    k_memory<<<MEM / 128, 256, 0, stream>>>(out + OFF_CWW, B2h, B2l, m_tm1, colmin,
                                            part, out + OFF_MEMORY,
                                            out + OFF_READ, use_part);
}